// Round 1
// baseline (1265.512 us; speedup 1.0000x reference)
//
#include <hip/hip_runtime.h>
#include <math.h>

#define BB 8
#define CC 256
#define HH 128
#define WW 128
#define NN (HH*WW)          // 16384
#define NBVEC 16

// ---------------- workspace layout (bytes) ----------------
// score  double[B][N]   @ 0         : 1048576
// simbuf double[B][N]   @ 1048576   : 1048576
// wsum   double[B][C]   @ 2097152   : 16384
// sumSim double[B]      @ 2113536   : 64
// rv     float [B][C]   @ 2113600   : 8192
// total ~2.03 MB

// Control kernel: one block per batch b, 256 threads.
//  - finalize previous iteration's reprVec = wsum / sumSim
//  - reset sumSim
//  - pick index (N/2 at iter 0, else first-argmax of score)
//  - selpos += 1 at index; gather rv[b][:] = x[b][:][ind]
__global__ void control_kernel(const float* __restrict__ x, float* __restrict__ out,
                               const double* __restrict__ score,
                               const double* __restrict__ wsum,
                               double* __restrict__ sumSim,
                               float* __restrict__ rv, int iter)
{
    const int b = blockIdx.x;
    const int t = threadIdx.x;   // 256 threads

    float* out_repr   = out;                                   // [NBVEC][B][C]
    float* out_selpos = out + (size_t)NBVEC*BB*CC + (size_t)NBVEC*BB*NN; // [B][N]

    __shared__ double s_val[256];
    __shared__ int    s_idx[256];
    __shared__ int    s_ind;

    if (iter > 0) {
        double ss = sumSim[b];
        if (t < CC) {
            out_repr[(size_t)(iter-1)*BB*CC + (size_t)b*CC + t] =
                (float)(wsum[(size_t)b*CC + t] / ss);
        }
    }
    __syncthreads();
    if (t == 0) sumSim[b] = 0.0;

    if (iter >= NBVEC) return;   // last call only finalizes

    if (iter == 0) {
        if (t == 0) s_ind = NN/2;
    } else {
        // first-occurrence argmax over score[b][:]
        double best = -1.0e300; int bidx = 0x7fffffff;
        for (int n = t; n < NN; n += 256) {
            double v = score[(size_t)b*NN + n];
            if (v > best) { best = v; bidx = n; }   // strict > keeps lowest n
        }
        s_val[t] = best; s_idx[t] = bidx;
        __syncthreads();
        for (int s = 128; s > 0; s >>= 1) {
            if (t < s) {
                double v2 = s_val[t+s]; int i2 = s_idx[t+s];
                if (v2 > s_val[t] || (v2 == s_val[t] && i2 < s_idx[t])) {
                    s_val[t] = v2; s_idx[t] = i2;
                }
            }
            __syncthreads();
        }
        if (t == 0) s_ind = s_idx[0];
    }
    __syncthreads();

    const int sel = s_ind;
    if (t == 0) out_selpos[(size_t)b*NN + sel] += 1.0f;
    if (t < CC) rv[(size_t)b*CC + t] = x[(size_t)b*CC*NN + (size_t)t*NN + sel];
}

// Phase 1: grid (N/256, B), 256 threads; thread-per-n.
// d^2 = sum_c (x - rv)^2 (fp64), sim = exp(-sqrt(d2+1e-12)/20),
// write sim (ws fp64 + output fp32), score update, block-reduce sumSim.
__global__ void phase1_kernel(const float* __restrict__ x, float* __restrict__ out,
                              double* __restrict__ score,
                              double* __restrict__ simbuf,
                              double* __restrict__ sumSim,
                              const float* __restrict__ rv, int iter)
{
    const int b = blockIdx.y;
    const int t = threadIdx.x;
    const int n = blockIdx.x * 256 + t;

    __shared__ float s_rv[CC];
    s_rv[t] = rv[(size_t)b*CC + t];
    __syncthreads();

    const float* xb = x + (size_t)b*CC*NN;
    double acc = 0.0;
    #pragma unroll 8
    for (int c = 0; c < CC; ++c) {
        double diff = (double)xb[(size_t)c*NN + n] - (double)s_rv[c];
        acc = fma(diff, diff, acc);
    }
    double d   = sqrt(acc + 1e-12);
    double sim = exp(-(d / 20.0));

    simbuf[(size_t)b*NN + n] = sim;
    float* out_sims = out + (size_t)NBVEC*BB*CC;   // [NBVEC][B][N]
    out_sims[(size_t)iter*BB*NN + (size_t)b*NN + n] = (float)sim;

    const size_t si = (size_t)b*NN + n;
    if (iter == 0) score[si] = 1.0 - sim;
    else           score[si] = (1.0 - sim) * score[si];

    __shared__ double s_red[256];
    s_red[t] = sim;
    __syncthreads();
    for (int s = 128; s > 0; s >>= 1) {
        if (t < s) s_red[t] += s_red[t+s];
        __syncthreads();
    }
    if (t == 0) atomicAdd(&sumSim[b], s_red[0]);
}

// Phase 2: grid (C, B), 256 threads; block owns (b,c):
// wsum[b][c] = sum_n sim[b][n] * x[b][c][n]   (fp64, no atomics)
__global__ void phase2_kernel(const float* __restrict__ x,
                              const double* __restrict__ simbuf,
                              double* __restrict__ wsum)
{
    const int b = blockIdx.y;
    const int c = blockIdx.x;
    const int t = threadIdx.x;

    const float*  xr = x + (size_t)b*CC*NN + (size_t)c*NN;
    const double* sr = simbuf + (size_t)b*NN;

    double acc = 0.0;
    #pragma unroll 4
    for (int n = t; n < NN; n += 256)
        acc = fma(sr[n], (double)xr[n], acc);

    __shared__ double s_red[256];
    s_red[t] = acc;
    __syncthreads();
    for (int s = 128; s > 0; s >>= 1) {
        if (t < s) s_red[t] += s_red[t+s];
        __syncthreads();
    }
    if (t == 0) wsum[(size_t)b*CC + c] = s_red[0];
}

extern "C" void kernel_launch(void* const* d_in, const int* in_sizes, int n_in,
                              void* d_out, int out_size, void* d_ws, size_t ws_size,
                              hipStream_t stream)
{
    const float* x = (const float*)d_in[0];
    // d_in[1] (prior) is provably unused: ind at i==0 is forced to N/2 and
    // score is overwritten with (1 - sim) at i==0, discarding the prior.
    // d_in[2] (nbVec) fixed at 16 by the problem shapes.
    float* out = (float*)d_out;

    char* ws = (char*)d_ws;
    double* score  = (double*)(ws);
    double* simbuf = (double*)(ws + 1048576);
    double* wsum   = (double*)(ws + 2097152);
    double* sumSim = (double*)(ws + 2113536);
    float*  rv     = (float*) (ws + 2113600);

    // d_out/d_ws are poisoned before every launch: zero what we accumulate into.
    float* out_selpos = out + (size_t)NBVEC*BB*CC + (size_t)NBVEC*BB*NN;
    hipMemsetAsync(out_selpos, 0, (size_t)BB*NN*sizeof(float), stream);
    hipMemsetAsync(sumSim, 0, BB*sizeof(double), stream);

    for (int i = 0; i <= NBVEC; ++i) {
        control_kernel<<<BB, 256, 0, stream>>>(x, out, score, wsum, sumSim, rv, i);
        if (i < NBVEC) {
            phase1_kernel<<<dim3(NN/256, BB), 256, 0, stream>>>(
                x, out, score, simbuf, sumSim, rv, i);
            phase2_kernel<<<dim3(CC, BB), 256, 0, stream>>>(x, simbuf, wsum);
        }
    }
}